// Round 22
// baseline (131.893 us; speedup 1.0000x reference)
//
#include <hip/hip_runtime.h>

// AttentionBlock: B=8, T=2048, D=K=V=512. Inputs fp32, OUTPUT fp32.
// out = x + einsum('bts,bsv->btv', softmax_over_t(mask(q@k^T))/sqrt(512), v)
// softmax is over axis=1 (query axis t) per key-column s — column softmax.
//
// R22 = R21 (best 131.7us) + k_out residual add reads Xb (bf16, 16MB)
// instead of Xf (fp32, 32MB) — halves k_out's X stream; bf16 rounding of
// the residual adds ~0.015 absmax (threshold 0.108, current 0.0156).

typedef __attribute__((ext_vector_type(4))) float f32x4;
typedef __attribute__((ext_vector_type(8))) short s16x8;
typedef __attribute__((ext_vector_type(4))) short s16x4;

#define SQRTK  22.627416997969522f   // sqrt(512)

__device__ __forceinline__ float bf2f(unsigned short u) {
    union { unsigned int i; float f; } c; c.i = ((unsigned int)u) << 16; return c.f;
}
__device__ __forceinline__ short f2bf(float f) {
    union { float f; unsigned int i; } c; c.f = f;
    unsigned int x = c.i;
    return (short)((x + 0x7fffu + ((x >> 16) & 1u)) >> 16);
}
// async global->LDS, 16B per lane. lds ptr must be wave-uniform (HW scatters
// lane l to base + l*16). Our [row][32] tiles are lane-linear: byte = tid*16.
__device__ __forceinline__ void gll16(const void* g, void* l) {
    __builtin_amdgcn_global_load_lds(
        (const __attribute__((address_space(1))) void*)g,
        (__attribute__((address_space(3))) void*)l, 16, 0, 0);
}

// ---------------------------------------------------------------------------
// Merged fp32->bf16 casts: X (2097152 f4-groups) then Wq|Wk -> Wqk, Wv.
// ---------------------------------------------------------------------------
__global__ __launch_bounds__(256) void k_casts(
    const float* __restrict__ x, const float* __restrict__ q,
    const float* __restrict__ k, const float* __restrict__ v,
    unsigned short* __restrict__ ox, unsigned short* __restrict__ oqk,
    unsigned short* __restrict__ ov)
{
    int i = blockIdx.x * 256 + threadIdx.x;   // 0..2293759
    const float* src; unsigned short* dst; int j;
    if (i < 2097152)      { src = x; dst = ox; j = i; }
    else {
        j = i - 2097152;
        if (j < 65536)       { src = q; dst = oqk; }
        else if (j < 131072) { src = k; dst = oqk + 262144; j -= 65536; }
        else                 { src = v; dst = ov; j -= 131072; }
    }
    f32x4 w = *(const f32x4*)(src + (size_t)j * 4);
    s16x4 o;
#pragma unroll
    for (int jj = 0; jj < 4; ++jj) o[jj] = f2bf(w[jj]);
    *(s16x4*)(dst + (size_t)j * 4) = o;
}

// ---------------------------------------------------------------------------
// Fused Q+K projection: C[16384][1024] = Xb[16384][512] . Wqk[1024][512]^T
// + bias(concat bq|bk). 128x128 tile, BK=64 (two 32-halves per barrier),
// 4 waves, dbuf, global_load_lds.
// ---------------------------------------------------------------------------
__global__ __launch_bounds__(256) void k_projqk(
    const unsigned short* __restrict__ Xb,   // [16384][512] bf16
    const unsigned short* __restrict__ Wqk,  // [1024][512] bf16
    const float* __restrict__ bq, const float* __restrict__ bk,
    unsigned short* __restrict__ C)          // [16384][1024] bf16
{
    __shared__ short la[2][2][128][32];
    __shared__ short lb[2][2][128][32];
    const int tid  = threadIdx.x;
    const int wave = tid >> 6, lane = tid & 63;
    const int wr = (wave >> 1) * 64, wc = (wave & 1) * 64;
    const int m0 = blockIdx.x * 128, n0 = blockIdx.y * 128;
    const int r0 = tid >> 2, c0 = (tid & 3) * 8;
    const int wvb = wave * 1024;   // wave-uniform LDS byte base
    const int frl = lane & 15, kb = (lane >> 4) * 8, rg4 = (lane >> 4) * 4;
    f32x4 acc[4][4] = {};

#define QK_STAGE(BUF, K0) { \
    _Pragma("unroll") for (int h = 0; h < 2; ++h) { \
        char* pa_ = (char*)(&la[BUF][h][0][0]) + wvb; \
        char* pb_ = (char*)(&lb[BUF][h][0][0]) + wvb; \
        gll16(Xb  + (size_t)(m0 + r0) * 512 + (K0) + h * 32 + c0, pa_); \
        gll16(Xb  + (size_t)(m0 + r0 + 64) * 512 + (K0) + h * 32 + c0, pa_ + 4096); \
        gll16(Wqk + (size_t)(n0 + r0) * 512 + (K0) + h * 32 + c0, pb_); \
        gll16(Wqk + (size_t)(n0 + r0 + 64) * 512 + (K0) + h * 32 + c0, pb_ + 4096); } }

    QK_STAGE(0, 0);
    __syncthreads();
    for (int ks = 0; ks < 8; ++ks) {
        const int cur = ks & 1;
        if (ks < 7) QK_STAGE(cur ^ 1, (ks + 1) * 64);
#pragma unroll
        for (int h = 0; h < 2; ++h) {
            s16x8 af[4], bfr[4];
#pragma unroll
            for (int i = 0; i < 4; ++i) af[i]  = *(const s16x8*)(&la[cur][h][wr + i * 16 + frl][kb]);
#pragma unroll
            for (int i = 0; i < 4; ++i) bfr[i] = *(const s16x8*)(&lb[cur][h][wc + i * 16 + frl][kb]);
#pragma unroll
            for (int mi = 0; mi < 4; ++mi)
#pragma unroll
                for (int ni = 0; ni < 4; ++ni)
                    acc[mi][ni] = __builtin_amdgcn_mfma_f32_16x16x32_bf16(af[mi], bfr[ni], acc[mi][ni], 0, 0, 0);
        }
        __syncthreads();
    }
#undef QK_STAGE
#pragma unroll
    for (int mi = 0; mi < 4; ++mi)
#pragma unroll
        for (int ni = 0; ni < 4; ++ni) {
            int col = n0 + wc + ni * 16 + frl;
            float bv = (col < 512) ? bq[col] : bk[col - 512];
#pragma unroll
            for (int r = 0; r < 4; ++r) {
                int row = m0 + wr + mi * 16 + rg4 + r;
                C[(size_t)row * 1024 + col] = f2bf(acc[mi][ni][r] + bv);
            }
        }
}

// ---------------------------------------------------------------------------
// V projection (transposed output) with fused softmax scale computed in a
// coalesced block prologue: ftl[c] = 1/(Z_{n0+c} * sqrt(512)), Z from pz.
// Vs[v][col] = bf16( (Wv.Xb^T + bv) * ftl[col-n0] ).
// ---------------------------------------------------------------------------
__global__ __launch_bounds__(256) void k_projv(
    const unsigned short* __restrict__ Wv,   // [512][512] bf16
    const unsigned short* __restrict__ Xb,   // [16384][512] bf16
    const float* __restrict__ bv,            // [512]
    const float* __restrict__ pz,            // [8*16][2048] partial col sums
    unsigned short* __restrict__ C)          // [512][16384] bf16 (scaled)
{
    __shared__ short la[2][128][32];
    __shared__ short lb[2][128][32];
    __shared__ float ftl[128];
    const int tid  = threadIdx.x;
    const int wave = tid >> 6, lane = tid & 63;
    const int wr = (wave >> 1) * 64, wc = (wave & 1) * 64;
    const int m0 = blockIdx.x * 128, n0 = blockIdx.y * 128;
    const int r0 = tid >> 2, c0 = (tid & 3) * 8;
    const int wvb = wave * 1024;
    const int frl = lane & 15, kb = (lane >> 4) * 8, rg4 = (lane >> 4) * 4;
    f32x4 acc[4][4] = {};

#define PV_STAGE(BUF, K0) { \
    char* pa_ = (char*)(&la[BUF][0][0]) + wvb; \
    char* pb_ = (char*)(&lb[BUF][0][0]) + wvb; \
    gll16(Wv + (size_t)(m0 + r0) * 512 + (K0) + c0, pa_); \
    gll16(Wv + (size_t)(m0 + r0 + 64) * 512 + (K0) + c0, pa_ + 4096); \
    gll16(Xb + (size_t)(n0 + r0) * 512 + (K0) + c0, pb_); \
    gll16(Xb + (size_t)(n0 + r0 + 64) * 512 + (K0) + c0, pb_ + 4096); }

    PV_STAGE(0, 0);
    // ft prologue: block cols n0..n0+127 live in one batch (n0 128-aligned).
    if (tid < 128) {
        const int col = n0 + tid;
        const int bb = col >> 11, ss = col & 2047;
        float Z = 0.f;
        for (int tc = ss >> 7; tc < 16; ++tc)
            Z += pz[(bb * 16 + tc) * 2048 + ss];       // coalesced across tid
        ftl[tid] = 1.0f / (Z * SQRTK);
    }
    __syncthreads();
    for (int ks = 0; ks < 16; ++ks) {
        const int cur = ks & 1;
        if (ks < 15) PV_STAGE(cur ^ 1, (ks + 1) * 32);
        s16x8 af[4], bfr[4];
#pragma unroll
        for (int i = 0; i < 4; ++i) af[i]  = *(const s16x8*)(&la[cur][wr + i * 16 + frl][kb]);
#pragma unroll
        for (int i = 0; i < 4; ++i) bfr[i] = *(const s16x8*)(&lb[cur][wc + i * 16 + frl][kb]);
#pragma unroll
        for (int mi = 0; mi < 4; ++mi)
#pragma unroll
            for (int ni = 0; ni < 4; ++ni)
                acc[mi][ni] = __builtin_amdgcn_mfma_f32_16x16x32_bf16(af[mi], bfr[ni], acc[mi][ni], 0, 0, 0);
        __syncthreads();
    }
#undef PV_STAGE
#pragma unroll
    for (int mi = 0; mi < 4; ++mi)
#pragma unroll
        for (int ni = 0; ni < 4; ++ni) {
            const int colL = wc + ni * 16 + frl;
            const int col  = n0 + colL;
            float fs = ftl[colL];
#pragma unroll
            for (int r = 0; r < 4; ++r) {
                int row = m0 + wr + mi * 16 + rg4 + r;
                C[(size_t)row * 16384 + col] = f2bf((acc[mi][ni][r] + bv[row]) * fs);
            }
        }
}

// ---------------------------------------------------------------------------
// Logits tile Q.K^T; stores P = exp(L) bf16 (masked -> 0) + per-tile column
// sum-of-exp partials. BK=64 (two 32-halves per barrier, k_out-style LDS).
// 1-D grid over 136 triangular tiles x 8 batches; batch = n&7 (XCD spread).
// ---------------------------------------------------------------------------
__global__ __launch_bounds__(256) void k_logits(
    const unsigned short* __restrict__ QK,  // [B*2048][1024] bf16
    unsigned short* __restrict__ Pc,        // [B][2048][2048] bf16
    float* __restrict__ pz)                 // [B*16][2048] partial col sums
{
    const int n = blockIdx.x;
    const int b = n & 7;
    const int p = n >> 3;                       // 0..135 triangular index
    int tt = (int)((sqrtf(8.f * p + 1.f) - 1.f) * 0.5f);
    while ((tt + 1) * (tt + 2) / 2 <= p) ++tt;
    while (tt * (tt + 1) / 2 > p) --tt;
    const int st = p - tt * (tt + 1) / 2;       // st <= tt
    const int t0 = tt * 128, s0 = st * 128;

    const unsigned short* A  = QK + (size_t)b * 2048 * 1024;        // Q cols
    const unsigned short* Bt = QK + (size_t)b * 2048 * 1024 + 512;  // K cols
    unsigned short* Pb = Pc + (size_t)b * 2048 * 2048;

    __shared__ short la[2][2][128][32];
    __shared__ short lb[2][2][128][32];
    __shared__ float sz[2][128];
    const int tid  = threadIdx.x;
    const int wave = tid >> 6, lane = tid & 63;
    const int wr = (wave >> 1) * 64, wc = (wave & 1) * 64;
    const int r0 = tid >> 2, c0 = (tid & 3) * 8;
    const int wvb = wave * 1024;
    const int frl = lane & 15, kb = (lane >> 4) * 8, rg4 = (lane >> 4) * 4;
    f32x4 acc[4][4] = {};

#define LG_STAGE(BUF, K0) { \
    _Pragma("unroll") for (int h = 0; h < 2; ++h) { \
        char* pa_ = (char*)(&la[BUF][h][0][0]) + wvb; \
        char* pb_ = (char*)(&lb[BUF][h][0][0]) + wvb; \
        gll16(A  + (size_t)(t0 + r0) * 1024 + (K0) + h * 32 + c0, pa_); \
        gll16(A  + (size_t)(t0 + r0 + 64) * 1024 + (K0) + h * 32 + c0, pa_ + 4096); \
        gll16(Bt + (size_t)(s0 + r0) * 1024 + (K0) + h * 32 + c0, pb_); \
        gll16(Bt + (size_t)(s0 + r0 + 64) * 1024 + (K0) + h * 32 + c0, pb_ + 4096); } }

    LG_STAGE(0, 0);
    __syncthreads();
    for (int ks = 0; ks < 8; ++ks) {
        const int cur = ks & 1;
        if (ks < 7) LG_STAGE(cur ^ 1, (ks + 1) * 64);
#pragma unroll
        for (int h = 0; h < 2; ++h) {
            s16x8 af[4], bfr[4];
#pragma unroll
            for (int i = 0; i < 4; ++i) af[i]  = *(const s16x8*)(&la[cur][h][wr + i * 16 + frl][kb]);
#pragma unroll
            for (int i = 0; i < 4; ++i) bfr[i] = *(const s16x8*)(&lb[cur][h][wc + i * 16 + frl][kb]);
#pragma unroll
            for (int mi = 0; mi < 4; ++mi)
#pragma unroll
                for (int ni = 0; ni < 4; ++ni)
                    acc[mi][ni] = __builtin_amdgcn_mfma_f32_16x16x32_bf16(af[mi], bfr[ni], acc[mi][ni], 0, 0, 0);
        }
        __syncthreads();
    }
#undef LG_STAGE

    // Epilogue: e = exp(L) in place (masked -> 0), column partial sums.
    float cz[4];
#pragma unroll
    for (int ni = 0; ni < 4; ++ni) {
        const int colg = s0 + wc + ni * 16 + frl;
        float zl = 0.f;
#pragma unroll
        for (int mi = 0; mi < 4; ++mi)
#pragma unroll
            for (int r = 0; r < 4; ++r) {
                int row = t0 + wr + mi * 16 + rg4 + r;
                float e = (colg <= row) ? __expf(acc[mi][ni][r]) : 0.f;
                acc[mi][ni][r] = e;
                zl += e;
            }
        zl += __shfl_xor(zl, 16);
        zl += __shfl_xor(zl, 32);    // sum over wave's 64 rows
        cz[ni] = zl;
    }
    if (lane < 16) {
#pragma unroll
        for (int ni = 0; ni < 4; ++ni)
            sz[wr >> 6][wc + ni * 16 + lane] = cz[ni];
    }
    __syncthreads();
    if (tid < 128)
        pz[(b * 16 + tt) * 2048 + s0 + tid] = sz[0][tid] + sz[1][tid];
    // Store P = exp(L) bf16 directly.
#pragma unroll
    for (int ni = 0; ni < 4; ++ni) {
        const int colg = s0 + wc + ni * 16 + frl;
#pragma unroll
        for (int mi = 0; mi < 4; ++mi)
#pragma unroll
            for (int r = 0; r < 4; ++r) {
                int row = t0 + wr + mi * 16 + rg4 + r;
                Pb[(size_t)row * 2048 + colg] = f2bf(acc[mi][ni][r]);
            }
    }
}

// ---------------------------------------------------------------------------
// out[b,t,v] = x[b,t,v] + sum_s P[t,s] * Vs[v, b*2048+s]   (Vs pre-scaled)
// Pure bf16 GEMM: both operands staged via global_load_lds into
// [buf][half][128][32] (64KB LDS), 64 cols per barrier, 32 MFMA/step.
// Residual read from Xb (bf16) — halves the X stream. LPT order
// (tt = 15-(n>>5)) + XCD-batch affinity (b = n&7). [R18 verified]
// ---------------------------------------------------------------------------
__global__ __launch_bounds__(256) void k_out(
    const unsigned short* __restrict__ Pc, // [B][2048][2048] bf16
    const unsigned short* __restrict__ Vs, // [512][B*2048] bf16 (scaled)
    const unsigned short* __restrict__ Xb, // [B*2048][512] bf16
    float* __restrict__ Y)                 // [B][2048][512] fp32
{
    __shared__ short la[2][2][128][32];   // [buf][half] P
    __shared__ short lb[2][2][128][32];   // [buf][half] Vs
    const int n  = blockIdx.x;            // 0..511
    const int tt = 15 - (n >> 5);         // LPT: tt=15 first
    const int b  = n & 7;                 // batch -> XCD affinity
    const int v  = (n >> 3) & 3;
    const int t0 = tt * 128, v0 = v * 128;
    const unsigned short* Pb = Pc + (size_t)b * 2048 * 2048;
    const int tid  = threadIdx.x;
    const int wave = tid >> 6, lane = tid & 63;
    const int wr = (wave >> 1) * 64, wc = (wave & 1) * 64;
    const int frl = lane & 15, kb = (lane >> 4) * 8, rg4 = (lane >> 4) * 4;
    const int r0 = tid >> 2, c0 = (tid & 3) * 8;
    const int wvb = wave * 1024;

    f32x4 acc[4][4] = {};
    const int nit = (tt + 1) * 2;    // 64-wide iterations (causal)

#define OUT_STAGE(BUF, IT) { \
    int sb = (IT) * 64; \
    _Pragma("unroll") for (int h = 0; h < 2; ++h) { \
        char* pa_ = (char*)(&la[BUF][h][0][0]) + wvb; \
        char* pb_ = (char*)(&lb[BUF][h][0][0]) + wvb; \
        gll16(Pb + (size_t)(t0 + r0) * 2048 + sb + h * 32 + c0, pa_); \
        gll16(Pb + (size_t)(t0 + r0 + 64) * 2048 + sb + h * 32 + c0, pa_ + 4096); \
        gll16(Vs + (size_t)(v0 + r0) * 16384 + b * 2048 + sb + h * 32 + c0, pb_); \
        gll16(Vs + (size_t)(v0 + r0 + 64) * 16384 + b * 2048 + sb + h * 32 + c0, pb_ + 4096); } }

    OUT_STAGE(0, 0);
    __syncthreads();
    for (int it = 0; it < nit; ++it) {
        const int cur = it & 1;
        if (it + 1 < nit) OUT_STAGE(cur ^ 1, it + 1);
#pragma unroll
        for (int h = 0; h < 2; ++h) {
            s16x8 af[4], bfr[4];
#pragma unroll
            for (int i = 0; i < 4; ++i) af[i]  = *(const s16x8*)(&la[cur][h][wr + i * 16 + frl][kb]);
#pragma unroll
            for (int i = 0; i < 4; ++i) bfr[i] = *(const s16x8*)(&lb[cur][h][wc + i * 16 + frl][kb]);
#pragma unroll
            for (int mi = 0; mi < 4; ++mi)
#pragma unroll
                for (int ni = 0; ni < 4; ++ni)
                    acc[mi][ni] = __builtin_amdgcn_mfma_f32_16x16x32_bf16(af[mi], bfr[ni], acc[mi][ni], 0, 0, 0);
        }
        __syncthreads();
    }
#undef OUT_STAGE

#pragma unroll
    for (int mi = 0; mi < 4; ++mi)
#pragma unroll
        for (int ni = 0; ni < 4; ++ni) {
            int col = v0 + wc + ni * 16 + frl;
#pragma unroll
            for (int r = 0; r < 4; ++r) {
                int row = t0 + wr + mi * 16 + rg4 + r;
                size_t o = ((size_t)b * 2048 + row) * 512 + col;
                Y[o] = acc[mi][ni][r] + bf2f(Xb[o]);
            }
        }
}

extern "C" void kernel_launch(void* const* d_in, const int* in_sizes, int n_in,
                              void* d_out, int out_size, void* d_ws, size_t ws_size,
                              hipStream_t stream) {
    const float* Xf  = (const float*)d_in[0];
    const float* Wkf = (const float*)d_in[1];
    const float* bkf = (const float*)d_in[2];
    const float* Wqf = (const float*)d_in[3];
    const float* bqf = (const float*)d_in[4];
    const float* Wvf = (const float*)d_in[5];
    const float* bvf = (const float*)d_in[6];
    float* Y = (float*)d_out;
    char* ws = (char*)d_ws;

    // workspace layout (bytes); total ~149 MB
    float*          pz   = (float*)(ws);                            // 1 MB [8*16][2048]
    unsigned short* Wqkb = (unsigned short*)(ws + 4194304);         // 1 MB  [1024][512]
    unsigned short* Wvb  = (unsigned short*)(ws + 5242880);         // 512 KB [512][512]
    unsigned short* Xb   = (unsigned short*)(ws + 6291456);         // 16 MB [16384][512]
    unsigned short* QKb  = (unsigned short*)(ws + 23068672);        // 32 MB [16384][1024]
    unsigned short* Vs   = (unsigned short*)(ws + 56623104);        // 16 MB [512][16384]
    unsigned short* Pc   = (unsigned short*)(ws + 73400320);        // 64 MB [8][2048][2048]

    dim3 blk(256);
    // merged casts: X -> bf16, weights -> bf16 (Wq|Wk fused, Wv separate)
    k_casts<<<dim3(8960), blk, 0, stream>>>(Xf, Wqf, Wkf, Wvf, Xb, Wqkb, Wvb);
    // QK = Xb.[Wq;Wk]^T + [bq;bk]  (BK=64)
    k_projqk<<<dim3(128, 8), blk, 0, stream>>>(Xb, Wqkb, bqf, bkf, QKb);
    // logits -> P = exp(L) bf16 + per-tile column sum partials (BK=64)
    k_logits<<<dim3(1088), blk, 0, stream>>>(QKb, Pc, pz);
    // Vs = (Wv.Xb^T + bv) / (Z*sqrt(512)) — ft from pz via coalesced prologue
    k_projv<<<dim3(4, 128), blk, 0, stream>>>(Wvb, Xb, bvf, pz, Vs);
    // P.Vs^T + residual(Xb) (pure GEMM, dual gll16, LPT + XCD affinity)
    k_out<<<dim3(512), blk, 0, stream>>>(Pc, Vs, Xb, Y);
}

// Round 23
// 123.281 us; speedup vs baseline: 1.0699x; 1.0699x over previous
//
#include <hip/hip_runtime.h>

// AttentionBlock: B=8, T=2048, D=K=V=512. Inputs fp32, OUTPUT fp32.
// out = x + einsum('bts,bsv->btv', softmax_over_t(mask(q@k^T))/sqrt(512), v)
// softmax is over axis=1 (query axis t) per key-column s — column softmax.
//
// R23 = R22 + k_out with 512-thread (8-wave) blocks at the SAME 128x128
// tile: waves/SIMD 2->4 (LDS still 64KB, 2 blocks/CU) so the per-iteration
// gll16->barrier drain overlaps across twice the waves. Per-wave output
// 64x32 (acc 32 VGPR); staging = 1 gll16/thread per operand-half.

typedef __attribute__((ext_vector_type(4))) float f32x4;
typedef __attribute__((ext_vector_type(8))) short s16x8;
typedef __attribute__((ext_vector_type(4))) short s16x4;

#define SQRTK  22.627416997969522f   // sqrt(512)

__device__ __forceinline__ float bf2f(unsigned short u) {
    union { unsigned int i; float f; } c; c.i = ((unsigned int)u) << 16; return c.f;
}
__device__ __forceinline__ short f2bf(float f) {
    union { float f; unsigned int i; } c; c.f = f;
    unsigned int x = c.i;
    return (short)((x + 0x7fffu + ((x >> 16) & 1u)) >> 16);
}
// async global->LDS, 16B per lane. lds ptr must be wave-uniform (HW scatters
// lane l to base + l*16). Our [row][32] tiles are lane-linear: byte = tid*16.
__device__ __forceinline__ void gll16(const void* g, void* l) {
    __builtin_amdgcn_global_load_lds(
        (const __attribute__((address_space(1))) void*)g,
        (__attribute__((address_space(3))) void*)l, 16, 0, 0);
}

// ---------------------------------------------------------------------------
// Merged fp32->bf16 casts: X (2097152 f4-groups) then Wq|Wk -> Wqk, Wv.
// ---------------------------------------------------------------------------
__global__ __launch_bounds__(256) void k_casts(
    const float* __restrict__ x, const float* __restrict__ q,
    const float* __restrict__ k, const float* __restrict__ v,
    unsigned short* __restrict__ ox, unsigned short* __restrict__ oqk,
    unsigned short* __restrict__ ov)
{
    int i = blockIdx.x * 256 + threadIdx.x;   // 0..2293759
    const float* src; unsigned short* dst; int j;
    if (i < 2097152)      { src = x; dst = ox; j = i; }
    else {
        j = i - 2097152;
        if (j < 65536)       { src = q; dst = oqk; }
        else if (j < 131072) { src = k; dst = oqk + 262144; j -= 65536; }
        else                 { src = v; dst = ov; j -= 131072; }
    }
    f32x4 w = *(const f32x4*)(src + (size_t)j * 4);
    s16x4 o;
#pragma unroll
    for (int jj = 0; jj < 4; ++jj) o[jj] = f2bf(w[jj]);
    *(s16x4*)(dst + (size_t)j * 4) = o;
}

// ---------------------------------------------------------------------------
// Fused Q+K projection: C[16384][1024] = Xb[16384][512] . Wqk[1024][512]^T
// + bias(concat bq|bk). 128x128 tile, BK=64 (two 32-halves per barrier),
// 4 waves, dbuf, global_load_lds.
// ---------------------------------------------------------------------------
__global__ __launch_bounds__(256) void k_projqk(
    const unsigned short* __restrict__ Xb,   // [16384][512] bf16
    const unsigned short* __restrict__ Wqk,  // [1024][512] bf16
    const float* __restrict__ bq, const float* __restrict__ bk,
    unsigned short* __restrict__ C)          // [16384][1024] bf16
{
    __shared__ short la[2][2][128][32];
    __shared__ short lb[2][2][128][32];
    const int tid  = threadIdx.x;
    const int wave = tid >> 6, lane = tid & 63;
    const int wr = (wave >> 1) * 64, wc = (wave & 1) * 64;
    const int m0 = blockIdx.x * 128, n0 = blockIdx.y * 128;
    const int r0 = tid >> 2, c0 = (tid & 3) * 8;
    const int wvb = wave * 1024;   // wave-uniform LDS byte base
    const int frl = lane & 15, kb = (lane >> 4) * 8, rg4 = (lane >> 4) * 4;
    f32x4 acc[4][4] = {};

#define QK_STAGE(BUF, K0) { \
    _Pragma("unroll") for (int h = 0; h < 2; ++h) { \
        char* pa_ = (char*)(&la[BUF][h][0][0]) + wvb; \
        char* pb_ = (char*)(&lb[BUF][h][0][0]) + wvb; \
        gll16(Xb  + (size_t)(m0 + r0) * 512 + (K0) + h * 32 + c0, pa_); \
        gll16(Xb  + (size_t)(m0 + r0 + 64) * 512 + (K0) + h * 32 + c0, pa_ + 4096); \
        gll16(Wqk + (size_t)(n0 + r0) * 512 + (K0) + h * 32 + c0, pb_); \
        gll16(Wqk + (size_t)(n0 + r0 + 64) * 512 + (K0) + h * 32 + c0, pb_ + 4096); } }

    QK_STAGE(0, 0);
    __syncthreads();
    for (int ks = 0; ks < 8; ++ks) {
        const int cur = ks & 1;
        if (ks < 7) QK_STAGE(cur ^ 1, (ks + 1) * 64);
#pragma unroll
        for (int h = 0; h < 2; ++h) {
            s16x8 af[4], bfr[4];
#pragma unroll
            for (int i = 0; i < 4; ++i) af[i]  = *(const s16x8*)(&la[cur][h][wr + i * 16 + frl][kb]);
#pragma unroll
            for (int i = 0; i < 4; ++i) bfr[i] = *(const s16x8*)(&lb[cur][h][wc + i * 16 + frl][kb]);
#pragma unroll
            for (int mi = 0; mi < 4; ++mi)
#pragma unroll
                for (int ni = 0; ni < 4; ++ni)
                    acc[mi][ni] = __builtin_amdgcn_mfma_f32_16x16x32_bf16(af[mi], bfr[ni], acc[mi][ni], 0, 0, 0);
        }
        __syncthreads();
    }
#undef QK_STAGE
#pragma unroll
    for (int mi = 0; mi < 4; ++mi)
#pragma unroll
        for (int ni = 0; ni < 4; ++ni) {
            int col = n0 + wc + ni * 16 + frl;
            float bv = (col < 512) ? bq[col] : bk[col - 512];
#pragma unroll
            for (int r = 0; r < 4; ++r) {
                int row = m0 + wr + mi * 16 + rg4 + r;
                C[(size_t)row * 1024 + col] = f2bf(acc[mi][ni][r] + bv);
            }
        }
}

// ---------------------------------------------------------------------------
// V projection (transposed output) with fused softmax scale computed in a
// coalesced block prologue: ftl[c] = 1/(Z_{n0+c} * sqrt(512)), Z from pz.
// Vs[v][col] = bf16( (Wv.Xb^T + bv) * ftl[col-n0] ).
// ---------------------------------------------------------------------------
__global__ __launch_bounds__(256) void k_projv(
    const unsigned short* __restrict__ Wv,   // [512][512] bf16
    const unsigned short* __restrict__ Xb,   // [16384][512] bf16
    const float* __restrict__ bv,            // [512]
    const float* __restrict__ pz,            // [8*16][2048] partial col sums
    unsigned short* __restrict__ C)          // [512][16384] bf16 (scaled)
{
    __shared__ short la[2][128][32];
    __shared__ short lb[2][128][32];
    __shared__ float ftl[128];
    const int tid  = threadIdx.x;
    const int wave = tid >> 6, lane = tid & 63;
    const int wr = (wave >> 1) * 64, wc = (wave & 1) * 64;
    const int m0 = blockIdx.x * 128, n0 = blockIdx.y * 128;
    const int r0 = tid >> 2, c0 = (tid & 3) * 8;
    const int wvb = wave * 1024;
    const int frl = lane & 15, kb = (lane >> 4) * 8, rg4 = (lane >> 4) * 4;
    f32x4 acc[4][4] = {};

#define PV_STAGE(BUF, K0) { \
    char* pa_ = (char*)(&la[BUF][0][0]) + wvb; \
    char* pb_ = (char*)(&lb[BUF][0][0]) + wvb; \
    gll16(Wv + (size_t)(m0 + r0) * 512 + (K0) + c0, pa_); \
    gll16(Wv + (size_t)(m0 + r0 + 64) * 512 + (K0) + c0, pa_ + 4096); \
    gll16(Xb + (size_t)(n0 + r0) * 512 + (K0) + c0, pb_); \
    gll16(Xb + (size_t)(n0 + r0 + 64) * 512 + (K0) + c0, pb_ + 4096); }

    PV_STAGE(0, 0);
    // ft prologue: block cols n0..n0+127 live in one batch (n0 128-aligned).
    if (tid < 128) {
        const int col = n0 + tid;
        const int bb = col >> 11, ss = col & 2047;
        float Z = 0.f;
        for (int tc = ss >> 7; tc < 16; ++tc)
            Z += pz[(bb * 16 + tc) * 2048 + ss];       // coalesced across tid
        ftl[tid] = 1.0f / (Z * SQRTK);
    }
    __syncthreads();
    for (int ks = 0; ks < 16; ++ks) {
        const int cur = ks & 1;
        if (ks < 15) PV_STAGE(cur ^ 1, (ks + 1) * 32);
        s16x8 af[4], bfr[4];
#pragma unroll
        for (int i = 0; i < 4; ++i) af[i]  = *(const s16x8*)(&la[cur][wr + i * 16 + frl][kb]);
#pragma unroll
        for (int i = 0; i < 4; ++i) bfr[i] = *(const s16x8*)(&lb[cur][wc + i * 16 + frl][kb]);
#pragma unroll
        for (int mi = 0; mi < 4; ++mi)
#pragma unroll
            for (int ni = 0; ni < 4; ++ni)
                acc[mi][ni] = __builtin_amdgcn_mfma_f32_16x16x32_bf16(af[mi], bfr[ni], acc[mi][ni], 0, 0, 0);
        __syncthreads();
    }
#undef PV_STAGE
#pragma unroll
    for (int mi = 0; mi < 4; ++mi)
#pragma unroll
        for (int ni = 0; ni < 4; ++ni) {
            const int colL = wc + ni * 16 + frl;
            const int col  = n0 + colL;
            float fs = ftl[colL];
#pragma unroll
            for (int r = 0; r < 4; ++r) {
                int row = m0 + wr + mi * 16 + rg4 + r;
                C[(size_t)row * 16384 + col] = f2bf((acc[mi][ni][r] + bv[row]) * fs);
            }
        }
}

// ---------------------------------------------------------------------------
// Logits tile Q.K^T; stores P = exp(L) bf16 (masked -> 0) + per-tile column
// sum-of-exp partials. BK=64 (two 32-halves per barrier, k_out-style LDS).
// 1-D grid over 136 triangular tiles x 8 batches; batch = n&7 (XCD spread).
// ---------------------------------------------------------------------------
__global__ __launch_bounds__(256) void k_logits(
    const unsigned short* __restrict__ QK,  // [B*2048][1024] bf16
    unsigned short* __restrict__ Pc,        // [B][2048][2048] bf16
    float* __restrict__ pz)                 // [B*16][2048] partial col sums
{
    const int n = blockIdx.x;
    const int b = n & 7;
    const int p = n >> 3;                       // 0..135 triangular index
    int tt = (int)((sqrtf(8.f * p + 1.f) - 1.f) * 0.5f);
    while ((tt + 1) * (tt + 2) / 2 <= p) ++tt;
    while (tt * (tt + 1) / 2 > p) --tt;
    const int st = p - tt * (tt + 1) / 2;       // st <= tt
    const int t0 = tt * 128, s0 = st * 128;

    const unsigned short* A  = QK + (size_t)b * 2048 * 1024;        // Q cols
    const unsigned short* Bt = QK + (size_t)b * 2048 * 1024 + 512;  // K cols
    unsigned short* Pb = Pc + (size_t)b * 2048 * 2048;

    __shared__ short la[2][2][128][32];
    __shared__ short lb[2][2][128][32];
    __shared__ float sz[2][128];
    const int tid  = threadIdx.x;
    const int wave = tid >> 6, lane = tid & 63;
    const int wr = (wave >> 1) * 64, wc = (wave & 1) * 64;
    const int r0 = tid >> 2, c0 = (tid & 3) * 8;
    const int wvb = wave * 1024;
    const int frl = lane & 15, kb = (lane >> 4) * 8, rg4 = (lane >> 4) * 4;
    f32x4 acc[4][4] = {};

#define LG_STAGE(BUF, K0) { \
    _Pragma("unroll") for (int h = 0; h < 2; ++h) { \
        char* pa_ = (char*)(&la[BUF][h][0][0]) + wvb; \
        char* pb_ = (char*)(&lb[BUF][h][0][0]) + wvb; \
        gll16(A  + (size_t)(t0 + r0) * 1024 + (K0) + h * 32 + c0, pa_); \
        gll16(A  + (size_t)(t0 + r0 + 64) * 1024 + (K0) + h * 32 + c0, pa_ + 4096); \
        gll16(Bt + (size_t)(s0 + r0) * 1024 + (K0) + h * 32 + c0, pb_); \
        gll16(Bt + (size_t)(s0 + r0 + 64) * 1024 + (K0) + h * 32 + c0, pb_ + 4096); } }

    LG_STAGE(0, 0);
    __syncthreads();
    for (int ks = 0; ks < 8; ++ks) {
        const int cur = ks & 1;
        if (ks < 7) LG_STAGE(cur ^ 1, (ks + 1) * 64);
#pragma unroll
        for (int h = 0; h < 2; ++h) {
            s16x8 af[4], bfr[4];
#pragma unroll
            for (int i = 0; i < 4; ++i) af[i]  = *(const s16x8*)(&la[cur][h][wr + i * 16 + frl][kb]);
#pragma unroll
            for (int i = 0; i < 4; ++i) bfr[i] = *(const s16x8*)(&lb[cur][h][wc + i * 16 + frl][kb]);
#pragma unroll
            for (int mi = 0; mi < 4; ++mi)
#pragma unroll
                for (int ni = 0; ni < 4; ++ni)
                    acc[mi][ni] = __builtin_amdgcn_mfma_f32_16x16x32_bf16(af[mi], bfr[ni], acc[mi][ni], 0, 0, 0);
        }
        __syncthreads();
    }
#undef LG_STAGE

    // Epilogue: e = exp(L) in place (masked -> 0), column partial sums.
    float cz[4];
#pragma unroll
    for (int ni = 0; ni < 4; ++ni) {
        const int colg = s0 + wc + ni * 16 + frl;
        float zl = 0.f;
#pragma unroll
        for (int mi = 0; mi < 4; ++mi)
#pragma unroll
            for (int r = 0; r < 4; ++r) {
                int row = t0 + wr + mi * 16 + rg4 + r;
                float e = (colg <= row) ? __expf(acc[mi][ni][r]) : 0.f;
                acc[mi][ni][r] = e;
                zl += e;
            }
        zl += __shfl_xor(zl, 16);
        zl += __shfl_xor(zl, 32);    // sum over wave's 64 rows
        cz[ni] = zl;
    }
    if (lane < 16) {
#pragma unroll
        for (int ni = 0; ni < 4; ++ni)
            sz[wr >> 6][wc + ni * 16 + lane] = cz[ni];
    }
    __syncthreads();
    if (tid < 128)
        pz[(b * 16 + tt) * 2048 + s0 + tid] = sz[0][tid] + sz[1][tid];
    // Store P = exp(L) bf16 directly.
#pragma unroll
    for (int ni = 0; ni < 4; ++ni) {
        const int colg = s0 + wc + ni * 16 + frl;
#pragma unroll
        for (int mi = 0; mi < 4; ++mi)
#pragma unroll
            for (int r = 0; r < 4; ++r) {
                int row = t0 + wr + mi * 16 + rg4 + r;
                Pb[(size_t)row * 2048 + colg] = f2bf(acc[mi][ni][r]);
            }
    }
}

// ---------------------------------------------------------------------------
// out[b,t,v] = x[b,t,v] + sum_s P[t,s] * Vs[v, b*2048+s]   (Vs pre-scaled)
// 512-thread (8-wave) blocks, SAME 128x128 tile: waves/SIMD 2->4 at 2
// blocks/CU (64KB LDS) to hide the gll16->barrier drain. Wave grid 2x4,
// per-wave output 64x32 (acc[4][2]). Staging: 512 threads cover [128][32]
// -> 1 gll16/thread per operand-half. LPT order + XCD-batch affinity.
// ---------------------------------------------------------------------------
__global__ __launch_bounds__(512) void k_out(
    const unsigned short* __restrict__ Pc, // [B][2048][2048] bf16
    const unsigned short* __restrict__ Vs, // [512][B*2048] bf16 (scaled)
    const unsigned short* __restrict__ Xb, // [B*2048][512] bf16
    float* __restrict__ Y)                 // [B][2048][512] fp32
{
    __shared__ short la[2][2][128][32];   // [buf][half] P
    __shared__ short lb[2][2][128][32];   // [buf][half] Vs
    const int n  = blockIdx.x;            // 0..511
    const int tt = 15 - (n >> 5);         // LPT: tt=15 first
    const int b  = n & 7;                 // batch -> XCD affinity
    const int v  = (n >> 3) & 3;
    const int t0 = tt * 128, v0 = v * 128;
    const unsigned short* Pb = Pc + (size_t)b * 2048 * 2048;
    const int tid  = threadIdx.x;
    const int wave = tid >> 6, lane = tid & 63;
    const int wr = (wave >> 2) * 64, wc = (wave & 3) * 32;   // 2x4 wave grid
    const int frl = lane & 15, kb = (lane >> 4) * 8, rg4 = (lane >> 4) * 4;
    const int r0 = tid >> 2, c0 = (tid & 3) * 8;   // 512 threads -> rows 0..127
    const int wvb = wave * 1024;

    f32x4 acc[4][2] = {};
    const int nit = (tt + 1) * 2;    // 64-wide iterations (causal)

#define OUT_STAGE(BUF, IT) { \
    int sb = (IT) * 64; \
    _Pragma("unroll") for (int h = 0; h < 2; ++h) { \
        char* pa_ = (char*)(&la[BUF][h][0][0]) + wvb; \
        char* pb_ = (char*)(&lb[BUF][h][0][0]) + wvb; \
        gll16(Pb + (size_t)(t0 + r0) * 2048 + sb + h * 32 + c0, pa_); \
        gll16(Vs + (size_t)(v0 + r0) * 16384 + b * 2048 + sb + h * 32 + c0, pb_); } }

    OUT_STAGE(0, 0);
    __syncthreads();
    for (int it = 0; it < nit; ++it) {
        const int cur = it & 1;
        if (it + 1 < nit) OUT_STAGE(cur ^ 1, it + 1);
#pragma unroll
        for (int h = 0; h < 2; ++h) {
            s16x8 af[4], bfr[2];
#pragma unroll
            for (int i = 0; i < 4; ++i) af[i]  = *(const s16x8*)(&la[cur][h][wr + i * 16 + frl][kb]);
#pragma unroll
            for (int i = 0; i < 2; ++i) bfr[i] = *(const s16x8*)(&lb[cur][h][wc + i * 16 + frl][kb]);
#pragma unroll
            for (int mi = 0; mi < 4; ++mi)
#pragma unroll
                for (int ni = 0; ni < 2; ++ni)
                    acc[mi][ni] = __builtin_amdgcn_mfma_f32_16x16x32_bf16(af[mi], bfr[ni], acc[mi][ni], 0, 0, 0);
        }
        __syncthreads();
    }
#undef OUT_STAGE

#pragma unroll
    for (int mi = 0; mi < 4; ++mi)
#pragma unroll
        for (int ni = 0; ni < 2; ++ni) {
            int col = v0 + wc + ni * 16 + frl;
#pragma unroll
            for (int r = 0; r < 4; ++r) {
                int row = t0 + wr + mi * 16 + rg4 + r;
                size_t o = ((size_t)b * 2048 + row) * 512 + col;
                Y[o] = acc[mi][ni][r] + bf2f(Xb[o]);
            }
        }
}

extern "C" void kernel_launch(void* const* d_in, const int* in_sizes, int n_in,
                              void* d_out, int out_size, void* d_ws, size_t ws_size,
                              hipStream_t stream) {
    const float* Xf  = (const float*)d_in[0];
    const float* Wkf = (const float*)d_in[1];
    const float* bkf = (const float*)d_in[2];
    const float* Wqf = (const float*)d_in[3];
    const float* bqf = (const float*)d_in[4];
    const float* Wvf = (const float*)d_in[5];
    const float* bvf = (const float*)d_in[6];
    float* Y = (float*)d_out;
    char* ws = (char*)d_ws;

    // workspace layout (bytes); total ~149 MB
    float*          pz   = (float*)(ws);                            // 1 MB [8*16][2048]
    unsigned short* Wqkb = (unsigned short*)(ws + 4194304);         // 1 MB  [1024][512]
    unsigned short* Wvb  = (unsigned short*)(ws + 5242880);         // 512 KB [512][512]
    unsigned short* Xb   = (unsigned short*)(ws + 6291456);         // 16 MB [16384][512]
    unsigned short* QKb  = (unsigned short*)(ws + 23068672);        // 32 MB [16384][1024]
    unsigned short* Vs   = (unsigned short*)(ws + 56623104);        // 16 MB [512][16384]
    unsigned short* Pc   = (unsigned short*)(ws + 73400320);        // 64 MB [8][2048][2048]

    dim3 blk(256);
    // merged casts: X -> bf16, weights -> bf16 (Wq|Wk fused, Wv separate)
    k_casts<<<dim3(8960), blk, 0, stream>>>(Xf, Wqf, Wkf, Wvf, Xb, Wqkb, Wvb);
    // QK = Xb.[Wq;Wk]^T + [bq;bk]  (BK=64)
    k_projqk<<<dim3(128, 8), blk, 0, stream>>>(Xb, Wqkb, bqf, bkf, QKb);
    // logits -> P = exp(L) bf16 + per-tile column sum partials (BK=64)
    k_logits<<<dim3(1088), blk, 0, stream>>>(QKb, Pc, pz);
    // Vs = (Wv.Xb^T + bv) / (Z*sqrt(512)) — ft from pz via coalesced prologue
    k_projv<<<dim3(4, 128), blk, 0, stream>>>(Wvb, Xb, bvf, pz, Vs);
    // P.Vs^T + residual(Xb) — 8-wave blocks, LPT + XCD-batch affinity
    k_out<<<dim3(512), dim3(512), 0, stream>>>(Pc, Vs, Xb, Y);
}